// Round 3
// baseline (34.933 us; speedup 1.0000x reference)
//
#include <hip/hip_runtime.h>
#include <hip/hip_bf16.h>
#include <math.h>

// CBOW negative-sampling loss, collapsed:
//   out = -( (1/B) * sum_b [ logsig(dot(emb_w[target[b]], c_b))
//                          + sum_k logsig(dot(emb_w[noise[b,k]], c_b)) ] )
//   c_b = mean_w ctx_w[context[b,w]]
// V=100000, D=128, B=16384, W=10, K=10.
//
// Partitioning: 32 lanes per batch row (each lane owns 4 floats of D=128),
// 2 rows per wave, 4 waves per block -> 8 rows/block, 2048 blocks
// -> 8192 waves = 32 waves/CU (occupancy cap). Random-gather latency needs
// the TLP; R2's 16-lane layout capped at 16 waves/CU.

#define CBOW_B 16384
#define CBOW_W 10
#define CBOW_K 10
#define CBOW_D 128
#define ROWS_PER_BLOCK 8
#define NBLOCKS (CBOW_B / ROWS_PER_BLOCK)   // 2048

__device__ __forceinline__ float log_sigmoid(float x) {
    const float t = __expf(-fabsf(x));
    return fminf(x, 0.0f) - __logf(1.0f + t);
}

__global__ __launch_bounds__(256) void cbow_main(
    const int* __restrict__ context,   // [B, W]
    const int* __restrict__ target,    // [B]
    const int* __restrict__ noise,     // [B, K]
    const float* __restrict__ emb_w,   // [V, D]
    const float* __restrict__ ctx_w,   // [V, D]
    float* __restrict__ block_sums)    // [NBLOCKS]
{
    const int wave = threadIdx.x >> 6;  // 0..3
    const int lane = threadIdx.x & 63;
    const int grp  = lane >> 5;         // 0..1: batch row within wave
    const int sub  = lane & 31;         // lane within 32-lane group
    const int b = blockIdx.x * ROWS_PER_BLOCK + wave * 2 + grp;
    const unsigned elem = sub * 4u;     // floats [elem, elem+4) of D=128

    // ---- vector index loads (40 B rows are 8 B aligned -> int2) ----
    const int2* cI = reinterpret_cast<const int2*>(&context[b * CBOW_W]);
    const int2 c01 = cI[0], c23 = cI[1], c45 = cI[2], c67 = cI[3], c89 = cI[4];
    const int2* nI = reinterpret_cast<const int2*>(&noise[b * CBOW_K]);
    const int2 n01 = nI[0], n23 = nI[1], n45 = nI[2], n67 = nI[3], n89 = nI[4];
    const int tgt = target[b];

    // ---- context mean-pool (float4 per lane); 32-bit gather offsets ----
    float cx = 0, cy = 0, cz = 0, cw = 0;
    #define CBOW_ACC(IDX) {                                                    \
        const float4 r = *reinterpret_cast<const float4*>(                     \
            ctx_w + ((unsigned)(IDX) * (unsigned)CBOW_D + elem));              \
        cx += r.x; cy += r.y; cz += r.z; cw += r.w; }
    CBOW_ACC(c01.x) CBOW_ACC(c01.y) CBOW_ACC(c23.x) CBOW_ACC(c23.y)
    CBOW_ACC(c45.x) CBOW_ACC(c45.y) CBOW_ACC(c67.x) CBOW_ACC(c67.y)
    CBOW_ACC(c89.x) CBOW_ACC(c89.y)
    #undef CBOW_ACC
    const float inv = 1.0f / CBOW_W;
    cx *= inv; cy *= inv; cz *= inv; cw *= inv;

    // ---- positive + negative scores ----
    float sum = 0.0f;
    #define CBOW_DOT(IDX) {                                                    \
        const float4 r = *reinterpret_cast<const float4*>(                     \
            emb_w + ((unsigned)(IDX) * (unsigned)CBOW_D + elem));              \
        float p = cx * r.x + cy * r.y + cz * r.z + cw * r.w;                   \
        p += __shfl_xor(p, 1, 64);                                             \
        p += __shfl_xor(p, 2, 64);                                             \
        p += __shfl_xor(p, 4, 64);                                             \
        p += __shfl_xor(p, 8, 64);                                             \
        p += __shfl_xor(p, 16, 64);                                            \
        sum += log_sigmoid(p); }
    CBOW_DOT(tgt)
    CBOW_DOT(n01.x) CBOW_DOT(n01.y) CBOW_DOT(n23.x) CBOW_DOT(n23.y)
    CBOW_DOT(n45.x) CBOW_DOT(n45.y) CBOW_DOT(n67.x) CBOW_DOT(n67.y)
    CBOW_DOT(n89.x) CBOW_DOT(n89.y)
    #undef CBOW_DOT

    // ---- combine the 2 groups of this wave ----
    sum += __shfl_xor(sum, 32, 64);     // every lane now holds wave total

    // ---- per-block partial sum (deterministic; no atomics) ----
    __shared__ float wsum[4];
    if (lane == 0) wsum[wave] = sum;
    __syncthreads();
    if (threadIdx.x == 0) {
        float s = 0.0f;
        #pragma unroll
        for (int i = 0; i < 4; ++i) s += wsum[i];
        block_sums[blockIdx.x] = s;
    }
}

__global__ __launch_bounds__(256) void cbow_finish(
    const float* __restrict__ block_sums, float* __restrict__ out)
{
    __shared__ double sh[256];
    double s = 0.0;
    for (int i = threadIdx.x; i < NBLOCKS; i += 256) s += (double)block_sums[i];
    sh[threadIdx.x] = s;
    __syncthreads();
    #pragma unroll
    for (int stride = 128; stride >= 1; stride >>= 1) {
        if (threadIdx.x < stride) sh[threadIdx.x] += sh[threadIdx.x + stride];
        __syncthreads();
    }
    if (threadIdx.x == 0) {
        out[0] = (float)(-sh[0] / (double)CBOW_B);
    }
}

extern "C" void kernel_launch(void* const* d_in, const int* in_sizes, int n_in,
                              void* d_out, int out_size, void* d_ws, size_t ws_size,
                              hipStream_t stream) {
    const int*   context = (const int*)d_in[0];   // [B, W]
    const int*   target  = (const int*)d_in[1];   // [B]
    const int*   noise   = (const int*)d_in[2];   // [B, K]
    const float* emb_w   = (const float*)d_in[3]; // [V, D]
    const float* ctx_w   = (const float*)d_in[4]; // [V, D]
    float*       out     = (float*)d_out;
    float*       block_sums = (float*)d_ws;       // NBLOCKS floats = 8 KiB

    cbow_main<<<NBLOCKS, 256, 0, stream>>>(context, target, noise, emb_w, ctx_w,
                                           block_sums);
    cbow_finish<<<1, 256, 0, stream>>>(block_sums, out);
}